// Round 3
// baseline (158.279 us; speedup 1.0000x reference)
//
#include <hip/hip_runtime.h>
#include <hip/hip_bf16.h>
#include <cstddef>

#define T_TOK 1024
#define D_DIM 1024
#define H_DIM 512
#define E_EXP 8
#define P_CAP 2560          // max padded pairs: 2048 + 8*63 = 2552 -> 2560
#define MAX_MT (P_CAP / 64) // 40 m-tile slots
#define LDA 72              // shorts per LDS row: 64 data + 8 pad (144B, 16B-aligned)

typedef __attribute__((ext_vector_type(4))) float    float4_t;
typedef __attribute__((ext_vector_type(4))) short    short4_t;
typedef __attribute__((ext_vector_type(8))) short    short8_t;
typedef __attribute__((ext_vector_type(4))) unsigned uint4_t;
typedef __attribute__((ext_vector_type(2))) unsigned uint2_t;

__device__ __forceinline__ short f2bf(float f) {
  union { float f; unsigned u; } v; v.f = f;
  unsigned u = v.u;
  u += 0x7FFFu + ((u >> 16) & 1u);
  return (short)(u >> 16);
}

// packed fp32x2 -> bf16x2 (v_cvt_pk_bf16_f32 on gfx950); low short = a, high = b
__device__ __forceinline__ unsigned pkbf(float a, float b) {
  union { __hip_bfloat162 h; unsigned u; } v;
  v.h = __float22bfloat162_rn(make_float2(a, b));
  return v.u;
}

// ------ weight conv: src[e][K][N] fp32 -> dst[e][row_off + n][k] bf16 -------
__global__ __launch_bounds__(256) void wconv_kernel(
    const float* __restrict__ src, short* __restrict__ dst,
    int K, int N, int ld_dst, int row_off, size_t src_es, size_t dst_es) {
  __shared__ float tile[64][68];
  const int e  = blockIdx.z;
  const int k0 = blockIdx.x * 64;
  const int n0 = blockIdx.y * 64;
  const int tid = threadIdx.x;
  const float* s = src + (size_t)e * src_es;
  // load 64k x 64n coalesced
  const int kr = tid >> 4, nc = (tid & 15) * 4;
  #pragma unroll
  for (int p = 0; p < 4; ++p) {
    int k = p * 16 + kr;
    float4_t v = *(const float4_t*)(s + (size_t)(k0 + k) * N + n0 + nc);
    *(float4_t*)&tile[k][nc] = v;
  }
  __syncthreads();
  // write transposed [n][k] bf16, 16B per thread-pass
  const int r8 = tid >> 3, c8 = tid & 7;
  short* d = dst + (size_t)e * dst_es;
  #pragma unroll
  for (int p = 0; p < 2; ++p) {
    int row = p * 32 + r8;
    uint4_t u;
    #pragma unroll
    for (int j = 0; j < 4; ++j)
      u[j] = pkbf(tile[c8 * 8 + 2 * j][row], tile[c8 * 8 + 2 * j + 1][row]);
    *(uint4_t*)(d + (size_t)(row_off + n0 + row) * ld_dst + k0 + c8 * 8) = u;
  }
}

// ---------------- router: logits -> softmax -> top2 (idx + score) ----------
__global__ __launch_bounds__(256) void router_kernel(
    const float* __restrict__ x, const float* __restrict__ gw,
    int* __restrict__ idx2, float* __restrict__ scale2) {
  const int wid  = threadIdx.x >> 6;
  const int lane = threadIdx.x & 63;
  const int t = blockIdx.x * 4 + wid;
  const float* xr = x + (size_t)t * D_DIM;
  float acc[E_EXP];
  #pragma unroll
  for (int e = 0; e < E_EXP; ++e) acc[e] = 0.f;
  for (int d = lane; d < D_DIM; d += 64) {
    float xv = xr[d];
    float4_t g0 = *(const float4_t*)(gw + d * E_EXP);
    float4_t g1 = *(const float4_t*)(gw + d * E_EXP + 4);
    acc[0] += xv * g0[0]; acc[1] += xv * g0[1];
    acc[2] += xv * g0[2]; acc[3] += xv * g0[3];
    acc[4] += xv * g1[0]; acc[5] += xv * g1[1];
    acc[6] += xv * g1[2]; acc[7] += xv * g1[3];
  }
  #pragma unroll
  for (int off = 32; off >= 1; off >>= 1) {
    #pragma unroll
    for (int e = 0; e < E_EXP; ++e) acc[e] += __shfl_down(acc[e], off, 64);
  }
  if (lane == 0) {
    float m = acc[0];
    #pragma unroll
    for (int e = 1; e < E_EXP; ++e) m = fmaxf(m, acc[e]);
    float p[E_EXP]; float s = 0.f;
    #pragma unroll
    for (int e = 0; e < E_EXP; ++e) { p[e] = __expf(acc[e] - m); s += p[e]; }
    float inv = 1.f / s;
    #pragma unroll
    for (int e = 0; e < E_EXP; ++e) p[e] *= inv;
    int i1 = 0;
    #pragma unroll
    for (int e = 1; e < E_EXP; ++e) if (p[e] > p[i1]) i1 = e;  // jax low-index tiebreak
    int i2 = (i1 == 0) ? 1 : 0;
    #pragma unroll
    for (int e = 0; e < E_EXP; ++e) {
      if (e == i1 || e == i2) continue;
      if (p[e] > p[i2]) i2 = e;
    }
    idx2[2 * t]     = i1;  scale2[2 * t]     = p[i1];
    idx2[2 * t + 1] = i2;  scale2[2 * t + 1] = p[i2];
  }
}

// ---- scan/assign: histogram -> aligned bases -> tile table -> pair lists ---
__global__ __launch_bounds__(256) void scan_kernel(
    const int* __restrict__ idx2, const float* __restrict__ scale2,
    int* __restrict__ pair_tok, float* __restrict__ pair_scale,
    int* __restrict__ meta) {
  __shared__ int cnt[E_EXP], base[E_EXP], cur[E_EXP];
  const int tid = threadIdx.x;
  if (tid < E_EXP) { cnt[tid] = 0; cur[tid] = 0; }
  for (int p = tid; p < P_CAP; p += 256) { pair_tok[p] = -1; pair_scale[p] = 0.f; }
  __syncthreads();
  for (int t = tid; t < T_TOK; t += 256) {
    atomicAdd(&cnt[idx2[2 * t]], 1);
    atomicAdd(&cnt[idx2[2 * t + 1]], 1);
  }
  __syncthreads();
  if (tid == 0) {
    int b = 0, g = 0;
    for (int e = 0; e < E_EXP; ++e) {
      base[e] = b;
      int al = (cnt[e] + 63) & ~63;
      for (int j = 0; j < al; j += 64) { meta[1 + g] = e; meta[41 + g] = b + j; ++g; }
      b += al;
    }
    meta[0] = g;  // n_mtiles
  }
  __syncthreads();
  for (int t = tid; t < T_TOK; t += 256) {
    #pragma unroll
    for (int s = 0; s < 2; ++s) {
      int e = idx2[2 * t + s];
      int p = base[e] + atomicAdd(&cur[e], 1);
      pair_tok[p] = t;
      pair_scale[p] = scale2[2 * t + s];
    }
  }
}

// ------- gemm1 (compacted): h[p][H] = silu((s*x_tok)@w1e) * ((s*x_tok)@w3e) -
__global__ __launch_bounds__(256, 2) void gemm1_kernel(
    const float* __restrict__ x, const short* __restrict__ w13t,
    const int* __restrict__ pair_tok, const float* __restrict__ pair_scale,
    const int* __restrict__ meta, short* __restrict__ h) {
  __shared__ short As[64 * LDA], B1s[64 * LDA], B3s[64 * LDA];
  const int mt = blockIdx.y;
  if (mt >= meta[0]) return;
  const int e    = meta[1 + mt];
  const int row0 = meta[41 + mt];
  const int n0   = blockIdx.x * 64;
  const int tid = threadIdx.x, lane = tid & 63, wid = tid >> 6;
  const int wr = wid >> 1, wc = wid & 1;
  const int q = lane >> 4, ln = lane & 15;
  const short* bsrc = w13t + (size_t)e * D_DIM * (2 * H_DIM);  // [1024 n][1024 k]

  // A staging: thread owns one 16-float k-segment of one row
  const int ar = tid >> 2, ak = tid & 3;
  const int   tokr = pair_tok[row0 + ar];
  const float sc   = pair_scale[row0 + ar];
  const float* xrow = x + (size_t)(tokr < 0 ? 0 : tokr) * D_DIM + ak * 16;

  // B staging: (row, k-unit)
  const int br = tid >> 3, bu = tid & 7;

  float4_t acc1[2][2], acc3[2][2];
  #pragma unroll
  for (int i = 0; i < 2; ++i)
    #pragma unroll
    for (int j = 0; j < 2; ++j) {
      acc1[i][j] = (float4_t){0.f, 0.f, 0.f, 0.f};
      acc3[i][j] = (float4_t){0.f, 0.f, 0.f, 0.f};
    }

  for (int k0 = 0; k0 < D_DIM; k0 += 64) {
    // ---- A: gather row, scale, convert, store [m][k]
    {
      float4_t v0 = *(const float4_t*)(xrow + k0);
      float4_t v1 = *(const float4_t*)(xrow + k0 + 4);
      float4_t v2 = *(const float4_t*)(xrow + k0 + 8);
      float4_t v3 = *(const float4_t*)(xrow + k0 + 12);
      uint4_t u0 = {pkbf(v0[0] * sc, v0[1] * sc), pkbf(v0[2] * sc, v0[3] * sc),
                    pkbf(v1[0] * sc, v1[1] * sc), pkbf(v1[2] * sc, v1[3] * sc)};
      uint4_t u1 = {pkbf(v2[0] * sc, v2[1] * sc), pkbf(v2[2] * sc, v2[3] * sc),
                    pkbf(v3[0] * sc, v3[1] * sc), pkbf(v3[2] * sc, v3[3] * sc)};
      *(uint4_t*)&As[ar * LDA + ak * 16]     = u0;
      *(uint4_t*)&As[ar * LDA + ak * 16 + 8] = u1;
    }
    // ---- B1/B3: pre-transposed bf16 rows, straight 16B copies
    #pragma unroll
    for (int p = 0; p < 2; ++p) {
      int row = p * 32 + br;
      uint4_t v1 = *(const uint4_t*)(bsrc + (size_t)(n0 + row) * D_DIM + k0 + bu * 8);
      uint4_t v3 = *(const uint4_t*)(bsrc + (size_t)(H_DIM + n0 + row) * D_DIM + k0 + bu * 8);
      *(uint4_t*)&B1s[row * LDA + bu * 8] = v1;
      *(uint4_t*)&B3s[row * LDA + bu * 8] = v3;
    }
    __syncthreads();

    short8_t af[2][2], b1f[2][2], b3f[2][2];
    #pragma unroll
    for (int i = 0; i < 2; ++i)
      #pragma unroll
      for (int kk = 0; kk < 2; ++kk)
        af[i][kk] = *(const short8_t*)&As[(wr * 32 + i * 16 + ln) * LDA + kk * 32 + q * 8];
    #pragma unroll
    for (int j = 0; j < 2; ++j)
      #pragma unroll
      for (int kk = 0; kk < 2; ++kk) {
        b1f[j][kk] = *(const short8_t*)&B1s[(wc * 32 + j * 16 + ln) * LDA + kk * 32 + q * 8];
        b3f[j][kk] = *(const short8_t*)&B3s[(wc * 32 + j * 16 + ln) * LDA + kk * 32 + q * 8];
      }
    #pragma unroll
    for (int i = 0; i < 2; ++i)
      #pragma unroll
      for (int j = 0; j < 2; ++j)
        #pragma unroll
        for (int kk = 0; kk < 2; ++kk) {
          acc1[i][j] = __builtin_amdgcn_mfma_f32_16x16x32_bf16(af[i][kk], b1f[j][kk], acc1[i][j], 0, 0, 0);
          acc3[i][j] = __builtin_amdgcn_mfma_f32_16x16x32_bf16(af[i][kk], b3f[j][kk], acc3[i][j], 0, 0, 0);
        }
    __syncthreads();
  }

  // ---- epilogue: silu(c1)*c3 -> h[pair][H]
  #pragma unroll
  for (int i = 0; i < 2; ++i) {
    int r_base = row0 + wr * 32 + i * 16 + q * 4;
    #pragma unroll
    for (int j = 0; j < 2; ++j) {
      int col = n0 + wc * 32 + j * 16 + ln;
      #pragma unroll
      for (int rr = 0; rr < 4; ++rr) {
        float c1 = acc1[i][j][rr];
        float c3 = acc3[i][j][rr];
        float sig = 1.f / (1.f + __expf(-c1));
        h[(size_t)(r_base + rr) * H_DIM + col] = f2bf(c1 * sig * c3);
      }
    }
  }
}

// -- gemm2 (compacted, fused combine): out[tok] += h[p][H] @ w2t[e] ----------
__global__ __launch_bounds__(256, 2) void gemm2_kernel(
    const short* __restrict__ h, const short* __restrict__ w2t,
    const int* __restrict__ pair_tok, const int* __restrict__ meta,
    float* __restrict__ out) {
  __shared__ short As[64 * LDA], Bs[64 * LDA];
  const int mt = blockIdx.y;
  if (mt >= meta[0]) return;
  const int e    = meta[1 + mt];
  const int row0 = meta[41 + mt];
  const int n0   = blockIdx.x * 64;
  const int tid = threadIdx.x, lane = tid & 63, wid = tid >> 6;
  const int wr = wid >> 1, wc = wid & 1;
  const int q = lane >> 4, ln = lane & 15;
  const short* bsrc = w2t + (size_t)e * D_DIM * H_DIM;  // [1024 n][512 k]

  const int ar = tid >> 2, ak = tid & 3;
  const short* hrow = h + (size_t)(row0 + ar) * H_DIM + ak * 16;
  const int br = tid >> 3, bu = tid & 7;

  float4_t acc[2][2];
  #pragma unroll
  for (int i = 0; i < 2; ++i)
    #pragma unroll
    for (int j = 0; j < 2; ++j) acc[i][j] = (float4_t){0.f, 0.f, 0.f, 0.f};

  for (int k0 = 0; k0 < H_DIM; k0 += 64) {
    // A: already bf16, straight 16B copies
    {
      uint4_t u0 = *(const uint4_t*)(hrow + k0);
      uint4_t u1 = *(const uint4_t*)(hrow + k0 + 8);
      *(uint4_t*)&As[ar * LDA + ak * 16]     = u0;
      *(uint4_t*)&As[ar * LDA + ak * 16 + 8] = u1;
    }
    // B: pre-transposed bf16 rows, straight 16B copies
    #pragma unroll
    for (int p = 0; p < 2; ++p) {
      int row = p * 32 + br;
      uint4_t v = *(const uint4_t*)(bsrc + (size_t)(n0 + row) * H_DIM + k0 + bu * 8);
      *(uint4_t*)&Bs[row * LDA + bu * 8] = v;
    }
    __syncthreads();

    short8_t af[2][2], bf[2][2];
    #pragma unroll
    for (int i = 0; i < 2; ++i)
      #pragma unroll
      for (int kk = 0; kk < 2; ++kk)
        af[i][kk] = *(const short8_t*)&As[(wr * 32 + i * 16 + ln) * LDA + kk * 32 + q * 8];
    #pragma unroll
    for (int j = 0; j < 2; ++j)
      #pragma unroll
      for (int kk = 0; kk < 2; ++kk)
        bf[j][kk] = *(const short8_t*)&Bs[(wc * 32 + j * 16 + ln) * LDA + kk * 32 + q * 8];
    #pragma unroll
    for (int i = 0; i < 2; ++i)
      #pragma unroll
      for (int j = 0; j < 2; ++j)
        #pragma unroll
        for (int kk = 0; kk < 2; ++kk)
          acc[i][j] = __builtin_amdgcn_mfma_f32_16x16x32_bf16(af[i][kk], bf[j][kk], acc[i][j], 0, 0, 0);
    __syncthreads();
  }

  // ---- epilogue: scatter-add into out[tok]; skip pad rows (tok < 0)
  #pragma unroll
  for (int i = 0; i < 2; ++i) {
    int r_base = row0 + wr * 32 + i * 16 + q * 4;
    #pragma unroll
    for (int rr = 0; rr < 4; ++rr) {
      int tok = pair_tok[r_base + rr];
      if (tok < 0) continue;
      float* orow = out + (size_t)tok * D_DIM;
      #pragma unroll
      for (int j = 0; j < 2; ++j) {
        int col = n0 + wc * 32 + j * 16 + ln;
        atomicAdd(orow + col, acc[i][j][rr]);
      }
    }
  }
}

extern "C" void kernel_launch(void* const* d_in, const int* in_sizes, int n_in,
                              void* d_out, int out_size, void* d_ws, size_t ws_size,
                              hipStream_t stream) {
  const float* x  = (const float*)d_in[0];   // [2,512,1024]
  const float* gw = (const float*)d_in[1];   // [1024,8]
  const float* w1 = (const float*)d_in[2];   // [8,1024,512] gate
  const float* w2 = (const float*)d_in[3];   // [8,512,1024] down
  const float* w3 = (const float*)d_in[4];   // [8,1024,512] up
  float* out = (float*)d_out;

  char* ws = (char*)d_ws;
  int*   idx2    = (int*)  (ws);              // 8KB
  float* scale2  = (float*)(ws + 8192);       // 8KB
  int*   ptok    = (int*)  (ws + 16384);      // 10KB (slot 16KB)
  float* pscale  = (float*)(ws + 32768);      // 10KB (slot 16KB)
  int*   meta    = (int*)  (ws + 49152);      // 512B (slot 16KB)
  short* h       = (short*)(ws + 65536);                            // 2.62MB
  short* w13t    = (short*)(ws + 65536 + (size_t)P_CAP * H_DIM * 2); // 16MB
  short* w2t     = w13t + (size_t)E_EXP * D_DIM * 2 * H_DIM;         // 8MB

  // weight pre-transpose+convert (every launch; ws is re-poisoned each call)
  wconv_kernel<<<dim3(16, 8, E_EXP), dim3(256), 0, stream>>>(
      w1, w13t, D_DIM, H_DIM, D_DIM, 0,     (size_t)D_DIM * H_DIM, (size_t)D_DIM * 2 * H_DIM);
  wconv_kernel<<<dim3(16, 8, E_EXP), dim3(256), 0, stream>>>(
      w3, w13t, D_DIM, H_DIM, D_DIM, H_DIM, (size_t)D_DIM * H_DIM, (size_t)D_DIM * 2 * H_DIM);
  wconv_kernel<<<dim3(8, 16, E_EXP), dim3(256), 0, stream>>>(
      w2, w2t, H_DIM, D_DIM, H_DIM, 0,      (size_t)H_DIM * D_DIM, (size_t)D_DIM * H_DIM);

  router_kernel<<<dim3(T_TOK / 4), dim3(256), 0, stream>>>(x, gw, idx2, scale2);
  scan_kernel<<<dim3(1), dim3(256), 0, stream>>>(idx2, scale2, ptok, pscale, meta);

  gemm1_kernel<<<dim3(H_DIM / 64, MAX_MT), dim3(256), 0, stream>>>(
      x, w13t, ptok, pscale, meta, h);

  hipMemsetAsync(out, 0, (size_t)T_TOK * D_DIM * sizeof(float), stream);
  gemm2_kernel<<<dim3(D_DIM / 64, MAX_MT), dim3(256), 0, stream>>>(
      h, w2t, ptok, meta, out);
}

// Round 4
// 152.009 us; speedup vs baseline: 1.0412x; 1.0412x over previous
//
#include <hip/hip_runtime.h>
#include <hip/hip_bf16.h>
#include <cstddef>

#define T_TOK 1024
#define D_DIM 1024
#define H_DIM 512
#define E_EXP 8
#define P_CAP 2560          // max padded pairs: 2048 + 8*63 = 2552 -> 2560
#define MAX_MT (P_CAP / 64) // 40 m-tile slots
#define LDA 72              // shorts per LDS row: 64 data + 8 pad (144B, 16B-aligned)

typedef __attribute__((ext_vector_type(4))) float    float4_t;
typedef __attribute__((ext_vector_type(8))) short    short8_t;
typedef __attribute__((ext_vector_type(4))) unsigned uint4_t;

__device__ __forceinline__ short f2bf(float f) {
  union { float f; unsigned u; } v; v.f = f;
  unsigned u = v.u;
  u += 0x7FFFu + ((u >> 16) & 1u);
  return (short)(u >> 16);
}

// packed fp32x2 -> bf16x2; low short = a, high = b
__device__ __forceinline__ unsigned pkbf(float a, float b) {
  union { __hip_bfloat162 h; unsigned u; } v;
  v.h = __float22bfloat162_rn(make_float2(a, b));
  return v.u;
}

// ------ merged weight conv: fp32 [e][K][N] -> bf16 [e][n][k] (transposed) ---
__global__ __launch_bounds__(256) void wconv_kernel(
    const float* __restrict__ w1, const float* __restrict__ w3,
    const float* __restrict__ w2, short* __restrict__ w13t,
    short* __restrict__ w2t) {
  __shared__ float tile[64][68];
  const int z = blockIdx.z;
  const float* src; short* dst; int N, ldd, row_off; size_t ses, des;
  if (z < 16) {
    if (blockIdx.y >= 8) return;            // N=512 -> 8 n-tiles
    int which = z >> 3, e = z & 7;
    src = (which ? w3 : w1) + (size_t)e * D_DIM * H_DIM;
    dst = w13t + (size_t)e * D_DIM * (2 * H_DIM);
    N = H_DIM; ldd = D_DIM; row_off = which ? H_DIM : 0;
  } else {
    if (blockIdx.x >= 8) return;            // K=512 -> 8 k-tiles
    int e = z - 16;
    src = w2 + (size_t)e * H_DIM * D_DIM;
    dst = w2t + (size_t)e * D_DIM * H_DIM;
    N = D_DIM; ldd = H_DIM; row_off = 0;
  }
  const int k0 = blockIdx.x * 64, n0 = blockIdx.y * 64;
  const int tid = threadIdx.x;
  const int kr = tid >> 4, nc = (tid & 15) * 4;
  #pragma unroll
  for (int p = 0; p < 4; ++p) {
    int k = p * 16 + kr;
    float4_t v = *(const float4_t*)(src + (size_t)(k0 + k) * N + n0 + nc);
    *(float4_t*)&tile[k][nc] = v;
  }
  __syncthreads();
  const int r8 = tid >> 3, c8 = tid & 7;
  #pragma unroll
  for (int p = 0; p < 2; ++p) {
    int row = p * 32 + r8;
    uint4_t u;
    #pragma unroll
    for (int j = 0; j < 4; ++j)
      u[j] = pkbf(tile[c8 * 8 + 2 * j][row], tile[c8 * 8 + 2 * j + 1][row]);
    *(uint4_t*)(dst + (size_t)(row_off + n0 + row) * ldd + k0 + c8 * 8) = u;
  }
}

// ---------------- router: logits -> softmax -> top2 (idx + score) ----------
__global__ __launch_bounds__(256) void router_kernel(
    const float* __restrict__ x, const float* __restrict__ gw,
    int* __restrict__ idx2, float* __restrict__ scale2) {
  const int wid  = threadIdx.x >> 6;
  const int lane = threadIdx.x & 63;
  const int t = blockIdx.x * 4 + wid;
  const float* xr = x + (size_t)t * D_DIM;
  float acc[E_EXP];
  #pragma unroll
  for (int e = 0; e < E_EXP; ++e) acc[e] = 0.f;
  for (int d = lane; d < D_DIM; d += 64) {
    float xv = xr[d];
    float4_t g0 = *(const float4_t*)(gw + d * E_EXP);
    float4_t g1 = *(const float4_t*)(gw + d * E_EXP + 4);
    acc[0] += xv * g0[0]; acc[1] += xv * g0[1];
    acc[2] += xv * g0[2]; acc[3] += xv * g0[3];
    acc[4] += xv * g1[0]; acc[5] += xv * g1[1];
    acc[6] += xv * g1[2]; acc[7] += xv * g1[3];
  }
  #pragma unroll
  for (int off = 32; off >= 1; off >>= 1) {
    #pragma unroll
    for (int e = 0; e < E_EXP; ++e) acc[e] += __shfl_down(acc[e], off, 64);
  }
  if (lane == 0) {
    float m = acc[0];
    #pragma unroll
    for (int e = 1; e < E_EXP; ++e) m = fmaxf(m, acc[e]);
    float p[E_EXP]; float s = 0.f;
    #pragma unroll
    for (int e = 0; e < E_EXP; ++e) { p[e] = __expf(acc[e] - m); s += p[e]; }
    float inv = 1.f / s;
    #pragma unroll
    for (int e = 0; e < E_EXP; ++e) p[e] *= inv;
    int i1 = 0;
    #pragma unroll
    for (int e = 1; e < E_EXP; ++e) if (p[e] > p[i1]) i1 = e;  // jax low-index tiebreak
    int i2 = (i1 == 0) ? 1 : 0;
    #pragma unroll
    for (int e = 0; e < E_EXP; ++e) {
      if (e == i1 || e == i2) continue;
      if (p[e] > p[i2]) i2 = e;
    }
    idx2[2 * t]     = i1;  scale2[2 * t]     = p[i1];
    idx2[2 * t + 1] = i2;  scale2[2 * t + 1] = p[i2];
  }
}

// ---- scan/assign: histogram -> aligned bases -> tile table -> pair lists ---
__global__ __launch_bounds__(256) void scan_kernel(
    const int* __restrict__ idx2, const float* __restrict__ scale2,
    int* __restrict__ pair_tok, float* __restrict__ pair_scale,
    int* __restrict__ meta) {
  __shared__ int cnt[E_EXP], base[E_EXP], cur[E_EXP];
  const int tid = threadIdx.x;
  if (tid < E_EXP) { cnt[tid] = 0; cur[tid] = 0; }
  for (int p = tid; p < P_CAP; p += 256) { pair_tok[p] = -1; pair_scale[p] = 0.f; }
  __syncthreads();
  for (int t = tid; t < T_TOK; t += 256) {
    atomicAdd(&cnt[idx2[2 * t]], 1);
    atomicAdd(&cnt[idx2[2 * t + 1]], 1);
  }
  __syncthreads();
  if (tid == 0) {
    int b = 0, g = 0;
    for (int e = 0; e < E_EXP; ++e) {
      base[e] = b;
      int al = (cnt[e] + 63) & ~63;
      for (int j = 0; j < al; j += 64) { meta[1 + g] = e; meta[41 + g] = b + j; ++g; }
      b += al;
    }
    meta[0] = g;  // n_mtiles
  }
  __syncthreads();
  for (int t = tid; t < T_TOK; t += 256) {
    #pragma unroll
    for (int s = 0; s < 2; ++s) {
      int e = idx2[2 * t + s];
      int p = base[e] + atomicAdd(&cur[e], 1);
      pair_tok[p] = t;
      pair_scale[p] = scale2[2 * t + s];
    }
  }
}

// ---- xsconv: xs[p][D] = bf16(scale[p] * x[tok[p]])  (pad rows -> zeros) ----
__global__ __launch_bounds__(256) void xsconv_kernel(
    const float* __restrict__ x, const int* __restrict__ pair_tok,
    const float* __restrict__ pair_scale, short* __restrict__ xs) {
  const int row = blockIdx.x * 8 + (threadIdx.x >> 5);
  const int seg = (threadIdx.x & 31) * 32;
  const int tok = pair_tok[row];
  const float sc = pair_scale[row];        // 0 for pad rows
  const float* src = x + (size_t)(tok < 0 ? 0 : tok) * D_DIM + seg;
  short* dst = xs + (size_t)row * D_DIM + seg;
  #pragma unroll
  for (int p = 0; p < 2; ++p) {
    float4_t v0 = *(const float4_t*)(src + p * 16);
    float4_t v1 = *(const float4_t*)(src + p * 16 + 4);
    float4_t v2 = *(const float4_t*)(src + p * 16 + 8);
    float4_t v3 = *(const float4_t*)(src + p * 16 + 12);
    uint4_t u0 = {pkbf(v0[0] * sc, v0[1] * sc), pkbf(v0[2] * sc, v0[3] * sc),
                  pkbf(v1[0] * sc, v1[1] * sc), pkbf(v1[2] * sc, v1[3] * sc)};
    uint4_t u1 = {pkbf(v2[0] * sc, v2[1] * sc), pkbf(v2[2] * sc, v2[3] * sc),
                  pkbf(v3[0] * sc, v3[1] * sc), pkbf(v3[2] * sc, v3[3] * sc)};
    *(uint4_t*)(dst + p * 16)     = u0;
    *(uint4_t*)(dst + p * 16 + 8) = u1;
  }
}

// ------- gemm1: h[p][H] = silu(xs@w1e) * (xs@w3e); 64m x 32n tiles ---------
// Register-prefetch + LDS double-buffer, ONE barrier per K-iter.
__global__ __launch_bounds__(256, 2) void gemm1_kernel(
    const short* __restrict__ xs, const short* __restrict__ w13t,
    const int* __restrict__ meta, short* __restrict__ h) {
  __shared__ short As[2][64 * LDA];   // 18.4 KB
  __shared__ short B1s[2][32 * LDA];  //  9.2 KB
  __shared__ short B3s[2][32 * LDA];  //  9.2 KB
  const int mt = blockIdx.y;
  if (mt >= meta[0]) return;
  const int e    = meta[1 + mt];
  const int row0 = meta[41 + mt];
  const int n0   = blockIdx.x * 32;
  const int tid = threadIdx.x, lane = tid & 63, wid = tid >> 6;
  const int wr = wid >> 1, wc = wid & 1;
  const int q = lane >> 4, ln = lane & 15;
  const short* bsrc = w13t + (size_t)e * D_DIM * (2 * H_DIM);

  const int ar = tid >> 2, ak = (tid & 3) * 16;
  const short* arow = xs + (size_t)(row0 + ar) * D_DIM + ak;
  const int br = tid >> 3, bu = (tid & 7) * 8;
  const short* b1p = bsrc + (size_t)(n0 + br) * D_DIM + bu;
  const short* b3p = bsrc + (size_t)(H_DIM + n0 + br) * D_DIM + bu;

  float4_t acc1[2], acc3[2];
  acc1[0] = acc1[1] = acc3[0] = acc3[1] = (float4_t){0.f, 0.f, 0.f, 0.f};

  uint4_t va0 = *(const uint4_t*)(arow);
  uint4_t va1 = *(const uint4_t*)(arow + 8);
  uint4_t vb1 = *(const uint4_t*)(b1p);
  uint4_t vb3 = *(const uint4_t*)(b3p);
  *(uint4_t*)&As [0][ar * LDA + ak] = va0;
  *(uint4_t*)&As [0][ar * LDA + ak + 8] = va1;
  *(uint4_t*)&B1s[0][br * LDA + bu] = vb1;
  *(uint4_t*)&B3s[0][br * LDA + bu] = vb3;
  __syncthreads();

  for (int k = 0; k < 16; ++k) {
    const int cur = k & 1, nxt = cur ^ 1;
    if (k < 15) {                        // issue k+1 loads early
      int k0 = (k + 1) * 64;
      va0 = *(const uint4_t*)(arow + k0);
      va1 = *(const uint4_t*)(arow + k0 + 8);
      vb1 = *(const uint4_t*)(b1p + k0);
      vb3 = *(const uint4_t*)(b3p + k0);
    }
    short8_t af[2][2], b1f[2], b3f[2];
    #pragma unroll
    for (int i = 0; i < 2; ++i)
      #pragma unroll
      for (int kk = 0; kk < 2; ++kk)
        af[i][kk] = *(const short8_t*)&As[cur][(wr * 32 + i * 16 + ln) * LDA + kk * 32 + q * 8];
    #pragma unroll
    for (int kk = 0; kk < 2; ++kk) {
      b1f[kk] = *(const short8_t*)&B1s[cur][(wc * 16 + ln) * LDA + kk * 32 + q * 8];
      b3f[kk] = *(const short8_t*)&B3s[cur][(wc * 16 + ln) * LDA + kk * 32 + q * 8];
    }
    #pragma unroll
    for (int i = 0; i < 2; ++i)
      #pragma unroll
      for (int kk = 0; kk < 2; ++kk) {
        acc1[i] = __builtin_amdgcn_mfma_f32_16x16x32_bf16(af[i][kk], b1f[kk], acc1[i], 0, 0, 0);
        acc3[i] = __builtin_amdgcn_mfma_f32_16x16x32_bf16(af[i][kk], b3f[kk], acc3[i], 0, 0, 0);
      }
    if (k < 15) {                        // store k+1 into other buffer
      *(uint4_t*)&As [nxt][ar * LDA + ak] = va0;
      *(uint4_t*)&As [nxt][ar * LDA + ak + 8] = va1;
      *(uint4_t*)&B1s[nxt][br * LDA + bu] = vb1;
      *(uint4_t*)&B3s[nxt][br * LDA + bu] = vb3;
    }
    __syncthreads();
  }

  #pragma unroll
  for (int i = 0; i < 2; ++i) {
    int r_base = row0 + wr * 32 + i * 16 + q * 4;
    int col = n0 + wc * 16 + ln;
    #pragma unroll
    for (int rr = 0; rr < 4; ++rr) {
      float c1 = acc1[i][rr];
      float c3 = acc3[i][rr];
      float sig = 1.f / (1.f + __expf(-c1));
      h[(size_t)(r_base + rr) * H_DIM + col] = f2bf(c1 * sig * c3);
    }
  }
}

// -- gemm2 (fused combine): out[tok] += h[p][H] @ w2t[e]; 64x64 tiles --------
__global__ __launch_bounds__(256, 2) void gemm2_kernel(
    const short* __restrict__ h, const short* __restrict__ w2t,
    const int* __restrict__ pair_tok, const int* __restrict__ meta,
    float* __restrict__ out) {
  __shared__ short As[2][64 * LDA];   // 18.4 KB
  __shared__ short Bs[2][64 * LDA];   // 18.4 KB
  const int mt = blockIdx.y;
  if (mt >= meta[0]) return;
  const int e    = meta[1 + mt];
  const int row0 = meta[41 + mt];
  const int n0   = blockIdx.x * 64;
  const int tid = threadIdx.x, lane = tid & 63, wid = tid >> 6;
  const int wr = wid >> 1, wc = wid & 1;
  const int q = lane >> 4, ln = lane & 15;
  const short* bsrc = w2t + (size_t)e * D_DIM * H_DIM;  // [1024 n][512 k]

  const int ar = tid >> 2, ak = (tid & 3) * 16;
  const short* arow = h + (size_t)(row0 + ar) * H_DIM + ak;
  const short* brow = bsrc + (size_t)(n0 + ar) * H_DIM + ak;

  float4_t acc[2][2];
  #pragma unroll
  for (int i = 0; i < 2; ++i)
    #pragma unroll
    for (int j = 0; j < 2; ++j) acc[i][j] = (float4_t){0.f, 0.f, 0.f, 0.f};

  uint4_t va0 = *(const uint4_t*)(arow);
  uint4_t va1 = *(const uint4_t*)(arow + 8);
  uint4_t vb0 = *(const uint4_t*)(brow);
  uint4_t vb1 = *(const uint4_t*)(brow + 8);
  *(uint4_t*)&As[0][ar * LDA + ak] = va0;
  *(uint4_t*)&As[0][ar * LDA + ak + 8] = va1;
  *(uint4_t*)&Bs[0][ar * LDA + ak] = vb0;
  *(uint4_t*)&Bs[0][ar * LDA + ak + 8] = vb1;
  __syncthreads();

  for (int k = 0; k < 8; ++k) {
    const int cur = k & 1, nxt = cur ^ 1;
    if (k < 7) {
      int k0 = (k + 1) * 64;
      va0 = *(const uint4_t*)(arow + k0);
      va1 = *(const uint4_t*)(arow + k0 + 8);
      vb0 = *(const uint4_t*)(brow + k0);
      vb1 = *(const uint4_t*)(brow + k0 + 8);
    }
    short8_t af[2][2], bf[2][2];
    #pragma unroll
    for (int i = 0; i < 2; ++i)
      #pragma unroll
      for (int kk = 0; kk < 2; ++kk) {
        af[i][kk] = *(const short8_t*)&As[cur][(wr * 32 + i * 16 + ln) * LDA + kk * 32 + q * 8];
        bf[i][kk] = *(const short8_t*)&Bs[cur][(wc * 32 + i * 16 + ln) * LDA + kk * 32 + q * 8];
      }
    #pragma unroll
    for (int i = 0; i < 2; ++i)
      #pragma unroll
      for (int j = 0; j < 2; ++j)
        #pragma unroll
        for (int kk = 0; kk < 2; ++kk)
          acc[i][j] = __builtin_amdgcn_mfma_f32_16x16x32_bf16(af[i][kk], bf[j][kk], acc[i][j], 0, 0, 0);
    if (k < 7) {
      *(uint4_t*)&As[nxt][ar * LDA + ak] = va0;
      *(uint4_t*)&As[nxt][ar * LDA + ak + 8] = va1;
      *(uint4_t*)&Bs[nxt][ar * LDA + ak] = vb0;
      *(uint4_t*)&Bs[nxt][ar * LDA + ak + 8] = vb1;
    }
    __syncthreads();
  }

  // ---- epilogue: scatter-add into out[tok]; skip pad rows (tok < 0)
  #pragma unroll
  for (int i = 0; i < 2; ++i) {
    int r_base = row0 + wr * 32 + i * 16 + q * 4;
    #pragma unroll
    for (int rr = 0; rr < 4; ++rr) {
      int tok = pair_tok[r_base + rr];
      if (tok < 0) continue;
      float* orow = out + (size_t)tok * D_DIM;
      #pragma unroll
      for (int j = 0; j < 2; ++j) {
        int col = n0 + wc * 32 + j * 16 + ln;
        atomicAdd(orow + col, acc[i][j][rr]);
      }
    }
  }
}

extern "C" void kernel_launch(void* const* d_in, const int* in_sizes, int n_in,
                              void* d_out, int out_size, void* d_ws, size_t ws_size,
                              hipStream_t stream) {
  const float* x  = (const float*)d_in[0];   // [2,512,1024]
  const float* gw = (const float*)d_in[1];   // [1024,8]
  const float* w1 = (const float*)d_in[2];   // [8,1024,512] gate
  const float* w2 = (const float*)d_in[3];   // [8,512,1024] down
  const float* w3 = (const float*)d_in[4];   // [8,1024,512] up
  float* out = (float*)d_out;

  char* ws = (char*)d_ws;
  int*   idx2    = (int*)  (ws);                       // 8KB
  float* scale2  = (float*)(ws + 8192);                // 8KB
  int*   ptok    = (int*)  (ws + 16384);               // 10KB (16KB slot)
  float* pscale  = (float*)(ws + 32768);               // 10KB (16KB slot)
  int*   meta    = (int*)  (ws + 49152);               // 512B (16KB slot)
  short* xs      = (short*)(ws + (1 << 16));           // 5.24 MB
  short* h       = (short*)(ws + (6u << 20));          // 2.62 MB
  short* w13t    = (short*)(ws + (9u << 20));          // 16.8 MB
  short* w2t     = (short*)(ws + (26u << 20));         // 8.4 MB

  wconv_kernel<<<dim3(16, 16, 24), dim3(256), 0, stream>>>(w1, w3, w2, w13t, w2t);
  router_kernel<<<dim3(T_TOK / 4), dim3(256), 0, stream>>>(x, gw, idx2, scale2);
  scan_kernel<<<dim3(1), dim3(256), 0, stream>>>(idx2, scale2, ptok, pscale, meta);
  xsconv_kernel<<<dim3(P_CAP / 8), dim3(256), 0, stream>>>(x, ptok, pscale, xs);

  gemm1_kernel<<<dim3(H_DIM / 32, MAX_MT), dim3(256), 0, stream>>>(xs, w13t, meta, h);

  hipMemsetAsync(out, 0, (size_t)T_TOK * D_DIM * sizeof(float), stream);
  gemm2_kernel<<<dim3(D_DIM / 64, MAX_MT), dim3(256), 0, stream>>>(h, w2t, ptok, meta, out);
}

// Round 5
// 150.729 us; speedup vs baseline: 1.0501x; 1.0085x over previous
//
#include <hip/hip_runtime.h>
#include <hip/hip_bf16.h>
#include <cstddef>

#define T_TOK 1024
#define D_DIM 1024
#define H_DIM 512
#define E_EXP 8
#define P_CAP 2560          // max padded pairs: 2048 + 8*63 = 2552 -> 2560
#define MAX_MT (P_CAP / 64) // 40 m-tile slots
#define LDA 72              // shorts per LDS row: 64 data + 8 pad (144B, 16B-aligned)

typedef __attribute__((ext_vector_type(4))) float    float4_t;
typedef __attribute__((ext_vector_type(8))) short    short8_t;
typedef __attribute__((ext_vector_type(4))) unsigned uint4_t;

__device__ __forceinline__ short f2bf(float f) {
  union { float f; unsigned u; } v; v.f = f;
  unsigned u = v.u;
  u += 0x7FFFu + ((u >> 16) & 1u);
  return (short)(u >> 16);
}

// packed fp32x2 -> bf16x2; low short = a, high = b
__device__ __forceinline__ unsigned pkbf(float a, float b) {
  union { __hip_bfloat162 h; unsigned u; } v;
  v.h = __float22bfloat162_rn(make_float2(a, b));
  return v.u;
}

// ---- prep: weight transpose+convert (z<24) + router (z==24) + out=0 (z==25)
__global__ __launch_bounds__(256) void prep_kernel(
    const float* __restrict__ w1, const float* __restrict__ w3,
    const float* __restrict__ w2, const float* __restrict__ x,
    const float* __restrict__ gw, short* __restrict__ w13t,
    short* __restrict__ w2t, int* __restrict__ idx2,
    float* __restrict__ scale2, float* __restrict__ out) {
  __shared__ float tile[64][68];
  const int z = blockIdx.z;
  const int tid = threadIdx.x;

  if (z < 24) {
    const float* src; short* dst; int N, ldd, row_off;
    if (z < 16) {
      if (blockIdx.y >= 8) return;          // N=512 -> 8 n-tiles
      int which = z >> 3, e = z & 7;
      src = (which ? w3 : w1) + (size_t)e * D_DIM * H_DIM;
      dst = w13t + (size_t)e * D_DIM * (2 * H_DIM);
      N = H_DIM; ldd = D_DIM; row_off = which ? H_DIM : 0;
    } else {
      if (blockIdx.x >= 8) return;          // K=512 -> 8 k-tiles
      int e = z - 16;
      src = w2 + (size_t)e * H_DIM * D_DIM;
      dst = w2t + (size_t)e * D_DIM * H_DIM;
      N = D_DIM; ldd = H_DIM; row_off = 0;
    }
    const int k0 = blockIdx.x * 64, n0 = blockIdx.y * 64;
    const int kr = tid >> 4, nc = (tid & 15) * 4;
    #pragma unroll
    for (int p = 0; p < 4; ++p) {
      int k = p * 16 + kr;
      float4_t v = *(const float4_t*)(src + (size_t)(k0 + k) * N + n0 + nc);
      *(float4_t*)&tile[k][nc] = v;
    }
    __syncthreads();
    const int r8 = tid >> 3, c8 = tid & 7;
    #pragma unroll
    for (int p = 0; p < 2; ++p) {
      int row = p * 32 + r8;
      uint4_t u;
      #pragma unroll
      for (int j = 0; j < 4; ++j)
        u[j] = pkbf(tile[c8 * 8 + 2 * j][row], tile[c8 * 8 + 2 * j + 1][row]);
      *(uint4_t*)(dst + (size_t)(row_off + n0 + row) * ldd + k0 + c8 * 8) = u;
    }
    return;
  }

  if (z == 25) {                            // zero out[] : 256 blocks x 16KB
    float4_t z4 = {0.f, 0.f, 0.f, 0.f};
    float4_t* o = (float4_t*)(out + ((size_t)(blockIdx.y * 16 + blockIdx.x)) * 4096);
    #pragma unroll
    for (int i = 0; i < 4; ++i) o[i * 256 + tid] = z4;
    return;
  }

  // z == 24: router, 4 tokens per block (one wave each)
  const int wid  = tid >> 6;
  const int lane = tid & 63;
  const int t = (blockIdx.y * 16 + blockIdx.x) * 4 + wid;
  const float* xr = x + (size_t)t * D_DIM;
  float acc[E_EXP];
  #pragma unroll
  for (int e = 0; e < E_EXP; ++e) acc[e] = 0.f;
  for (int d = lane; d < D_DIM; d += 64) {
    float xv = xr[d];
    float4_t g0 = *(const float4_t*)(gw + d * E_EXP);
    float4_t g1 = *(const float4_t*)(gw + d * E_EXP + 4);
    acc[0] += xv * g0[0]; acc[1] += xv * g0[1];
    acc[2] += xv * g0[2]; acc[3] += xv * g0[3];
    acc[4] += xv * g1[0]; acc[5] += xv * g1[1];
    acc[6] += xv * g1[2]; acc[7] += xv * g1[3];
  }
  #pragma unroll
  for (int off = 32; off >= 1; off >>= 1) {
    #pragma unroll
    for (int e = 0; e < E_EXP; ++e) acc[e] += __shfl_down(acc[e], off, 64);
  }
  if (lane == 0) {
    float m = acc[0];
    #pragma unroll
    for (int e = 1; e < E_EXP; ++e) m = fmaxf(m, acc[e]);
    float p[E_EXP]; float s = 0.f;
    #pragma unroll
    for (int e = 0; e < E_EXP; ++e) { p[e] = __expf(acc[e] - m); s += p[e]; }
    float inv = 1.f / s;
    #pragma unroll
    for (int e = 0; e < E_EXP; ++e) p[e] *= inv;
    int i1 = 0;
    #pragma unroll
    for (int e = 1; e < E_EXP; ++e) if (p[e] > p[i1]) i1 = e;  // jax low-index tiebreak
    int i2 = (i1 == 0) ? 1 : 0;
    #pragma unroll
    for (int e = 0; e < E_EXP; ++e) {
      if (e == i1 || e == i2) continue;
      if (p[e] > p[i2]) i2 = e;
    }
    idx2[2 * t]     = i1;  scale2[2 * t]     = p[i1];
    idx2[2 * t + 1] = i2;  scale2[2 * t + 1] = p[i2];
  }
}

// ---- scan/assign: histogram -> aligned bases -> tile table -> pair lists ---
__global__ __launch_bounds__(256) void scan_kernel(
    const int* __restrict__ idx2, const float* __restrict__ scale2,
    int* __restrict__ pair_tok, float* __restrict__ pair_scale,
    int* __restrict__ meta) {
  __shared__ int cnt[E_EXP], base[E_EXP], cur[E_EXP];
  const int tid = threadIdx.x;
  if (tid < E_EXP) { cnt[tid] = 0; cur[tid] = 0; }
  for (int p = tid; p < P_CAP; p += 256) { pair_tok[p] = -1; pair_scale[p] = 0.f; }
  __syncthreads();
  for (int t = tid; t < T_TOK; t += 256) {
    atomicAdd(&cnt[idx2[2 * t]], 1);
    atomicAdd(&cnt[idx2[2 * t + 1]], 1);
  }
  __syncthreads();
  if (tid == 0) {
    int b = 0, g = 0;
    for (int e = 0; e < E_EXP; ++e) {
      base[e] = b;
      int al = (cnt[e] + 63) & ~63;
      for (int j = 0; j < al; j += 64) { meta[1 + g] = e; meta[41 + g] = b + j; ++g; }
      b += al;
    }
    meta[0] = g;  // n_mtiles
  }
  __syncthreads();
  for (int t = tid; t < T_TOK; t += 256) {
    #pragma unroll
    for (int s = 0; s < 2; ++s) {
      int e = idx2[2 * t + s];
      int p = base[e] + atomicAdd(&cur[e], 1);
      pair_tok[p] = t;
      pair_scale[p] = scale2[2 * t + s];
    }
  }
}

// ------- gemm1: h[p][H] = silu((s*x)@w1e) * ((s*x)@w3e); 64m x 32n ---------
// Single-buffer LDS (18.4KB) at 4 blocks/CU for latency hiding via TLP.
__global__ __launch_bounds__(256, 4) void gemm1_kernel(
    const float* __restrict__ x, const short* __restrict__ w13t,
    const int* __restrict__ pair_tok, const float* __restrict__ pair_scale,
    const int* __restrict__ meta, short* __restrict__ h) {
  __shared__ short As[64 * LDA];    // 9.2 KB
  __shared__ short B1s[32 * LDA];   // 4.6 KB
  __shared__ short B3s[32 * LDA];   // 4.6 KB
  const int mt = blockIdx.y;
  if (mt >= meta[0]) return;
  const int e    = meta[1 + mt];
  const int row0 = meta[41 + mt];
  const int n0   = blockIdx.x * 32;
  const int tid = threadIdx.x, lane = tid & 63, wid = tid >> 6;
  const int wr = wid >> 1, wc = wid & 1;
  const int q = lane >> 4, ln = lane & 15;
  const short* bsrc = w13t + (size_t)e * D_DIM * (2 * H_DIM);

  // A staging: thread owns one 16-float k-segment of one row (gather + scale)
  const int ar = tid >> 2, ak = (tid & 3) * 16;
  const int   tokr = pair_tok[row0 + ar];
  const float sc   = pair_scale[row0 + ar];     // 0 for pad rows -> zeros
  const float* xrow = x + (size_t)(tokr < 0 ? 0 : tokr) * D_DIM + ak;
  // B staging: thread owns one 8-short k-unit of one row
  const int br = tid >> 3, bu = (tid & 7) * 8;
  const short* b1p = bsrc + (size_t)(n0 + br) * D_DIM + bu;
  const short* b3p = bsrc + (size_t)(H_DIM + n0 + br) * D_DIM + bu;

  float4_t acc1[2], acc3[2];
  acc1[0] = acc1[1] = acc3[0] = acc3[1] = (float4_t){0.f, 0.f, 0.f, 0.f};

  for (int k0 = 0; k0 < D_DIM; k0 += 64) {
    float4_t v0 = *(const float4_t*)(xrow + k0);
    float4_t v1 = *(const float4_t*)(xrow + k0 + 4);
    float4_t v2 = *(const float4_t*)(xrow + k0 + 8);
    float4_t v3 = *(const float4_t*)(xrow + k0 + 12);
    uint4_t vb1 = *(const uint4_t*)(b1p + k0);
    uint4_t vb3 = *(const uint4_t*)(b3p + k0);
    uint4_t u0 = {pkbf(v0[0] * sc, v0[1] * sc), pkbf(v0[2] * sc, v0[3] * sc),
                  pkbf(v1[0] * sc, v1[1] * sc), pkbf(v1[2] * sc, v1[3] * sc)};
    uint4_t u1 = {pkbf(v2[0] * sc, v2[1] * sc), pkbf(v2[2] * sc, v2[3] * sc),
                  pkbf(v3[0] * sc, v3[1] * sc), pkbf(v3[2] * sc, v3[3] * sc)};
    *(uint4_t*)&As[ar * LDA + ak]     = u0;
    *(uint4_t*)&As[ar * LDA + ak + 8] = u1;
    *(uint4_t*)&B1s[br * LDA + bu] = vb1;
    *(uint4_t*)&B3s[br * LDA + bu] = vb3;
    __syncthreads();

    short8_t af[2][2], b1f[2], b3f[2];
    #pragma unroll
    for (int i = 0; i < 2; ++i)
      #pragma unroll
      for (int kk = 0; kk < 2; ++kk)
        af[i][kk] = *(const short8_t*)&As[(wr * 32 + i * 16 + ln) * LDA + kk * 32 + q * 8];
    #pragma unroll
    for (int kk = 0; kk < 2; ++kk) {
      b1f[kk] = *(const short8_t*)&B1s[(wc * 16 + ln) * LDA + kk * 32 + q * 8];
      b3f[kk] = *(const short8_t*)&B3s[(wc * 16 + ln) * LDA + kk * 32 + q * 8];
    }
    #pragma unroll
    for (int i = 0; i < 2; ++i)
      #pragma unroll
      for (int kk = 0; kk < 2; ++kk) {
        acc1[i] = __builtin_amdgcn_mfma_f32_16x16x32_bf16(af[i][kk], b1f[kk], acc1[i], 0, 0, 0);
        acc3[i] = __builtin_amdgcn_mfma_f32_16x16x32_bf16(af[i][kk], b3f[kk], acc3[i], 0, 0, 0);
      }
    __syncthreads();
  }

  #pragma unroll
  for (int i = 0; i < 2; ++i) {
    int r_base = row0 + wr * 32 + i * 16 + q * 4;
    int col = n0 + wc * 16 + ln;
    #pragma unroll
    for (int rr = 0; rr < 4; ++rr) {
      float c1 = acc1[i][rr];
      float c3 = acc3[i][rr];
      float sig = 1.f / (1.f + __expf(-c1));
      h[(size_t)(r_base + rr) * H_DIM + col] = f2bf(c1 * sig * c3);
    }
  }
}

// -- gemm2 (fused combine): out[tok] += h[p][H] @ w2t[e]; 64x64 tiles --------
__global__ __launch_bounds__(256, 4) void gemm2_kernel(
    const short* __restrict__ h, const short* __restrict__ w2t,
    const int* __restrict__ pair_tok, const int* __restrict__ meta,
    float* __restrict__ out) {
  __shared__ short As[64 * LDA];   // 9.2 KB
  __shared__ short Bs[64 * LDA];   // 9.2 KB
  const int mt = blockIdx.y;
  if (mt >= meta[0]) return;
  const int e    = meta[1 + mt];
  const int row0 = meta[41 + mt];
  const int n0   = blockIdx.x * 64;
  const int tid = threadIdx.x, lane = tid & 63, wid = tid >> 6;
  const int wr = wid >> 1, wc = wid & 1;
  const int q = lane >> 4, ln = lane & 15;
  const short* bsrc = w2t + (size_t)e * D_DIM * H_DIM;  // [1024 n][512 k]

  const int ar = tid >> 2, ak = (tid & 3) * 16;
  const short* arow = h + (size_t)(row0 + ar) * H_DIM + ak;
  const short* brow = bsrc + (size_t)(n0 + ar) * H_DIM + ak;

  float4_t acc[2][2];
  #pragma unroll
  for (int i = 0; i < 2; ++i)
    #pragma unroll
    for (int j = 0; j < 2; ++j) acc[i][j] = (float4_t){0.f, 0.f, 0.f, 0.f};

  for (int k0 = 0; k0 < H_DIM; k0 += 64) {
    uint4_t va0 = *(const uint4_t*)(arow + k0);
    uint4_t va1 = *(const uint4_t*)(arow + k0 + 8);
    uint4_t vb0 = *(const uint4_t*)(brow + k0);
    uint4_t vb1 = *(const uint4_t*)(brow + k0 + 8);
    *(uint4_t*)&As[ar * LDA + ak]     = va0;
    *(uint4_t*)&As[ar * LDA + ak + 8] = va1;
    *(uint4_t*)&Bs[ar * LDA + ak]     = vb0;
    *(uint4_t*)&Bs[ar * LDA + ak + 8] = vb1;
    __syncthreads();

    short8_t af[2][2], bf[2][2];
    #pragma unroll
    for (int i = 0; i < 2; ++i)
      #pragma unroll
      for (int kk = 0; kk < 2; ++kk) {
        af[i][kk] = *(const short8_t*)&As[(wr * 32 + i * 16 + ln) * LDA + kk * 32 + q * 8];
        bf[i][kk] = *(const short8_t*)&Bs[(wc * 32 + i * 16 + ln) * LDA + kk * 32 + q * 8];
      }
    #pragma unroll
    for (int i = 0; i < 2; ++i)
      #pragma unroll
      for (int j = 0; j < 2; ++j)
        #pragma unroll
        for (int kk = 0; kk < 2; ++kk)
          acc[i][j] = __builtin_amdgcn_mfma_f32_16x16x32_bf16(af[i][kk], bf[j][kk], acc[i][j], 0, 0, 0);
    __syncthreads();
  }

  // ---- epilogue: scatter-add into out[tok]; skip pad rows (tok < 0)
  #pragma unroll
  for (int i = 0; i < 2; ++i) {
    int r_base = row0 + wr * 32 + i * 16 + q * 4;
    #pragma unroll
    for (int rr = 0; rr < 4; ++rr) {
      int tok = pair_tok[r_base + rr];
      if (tok < 0) continue;
      float* orow = out + (size_t)tok * D_DIM;
      #pragma unroll
      for (int j = 0; j < 2; ++j) {
        int col = n0 + wc * 32 + j * 16 + ln;
        atomicAdd(orow + col, acc[i][j][rr]);
      }
    }
  }
}

extern "C" void kernel_launch(void* const* d_in, const int* in_sizes, int n_in,
                              void* d_out, int out_size, void* d_ws, size_t ws_size,
                              hipStream_t stream) {
  const float* x  = (const float*)d_in[0];   // [2,512,1024]
  const float* gw = (const float*)d_in[1];   // [1024,8]
  const float* w1 = (const float*)d_in[2];   // [8,1024,512] gate
  const float* w2 = (const float*)d_in[3];   // [8,512,1024] down
  const float* w3 = (const float*)d_in[4];   // [8,1024,512] up
  float* out = (float*)d_out;

  char* ws = (char*)d_ws;
  int*   idx2    = (int*)  (ws);                       // 8KB
  float* scale2  = (float*)(ws + 8192);                // 8KB
  int*   ptok    = (int*)  (ws + 16384);               // 10KB (16KB slot)
  float* pscale  = (float*)(ws + 32768);               // 10KB (16KB slot)
  int*   meta    = (int*)  (ws + 49152);               // 512B (16KB slot)
  short* h       = (short*)(ws + (1u << 20));          // 2.62 MB
  short* w13t    = (short*)(ws + (4u << 20));          // 16.8 MB
  short* w2t     = (short*)(ws + (21u << 20));         // 8.4 MB

  // prep: all weight conv planes + router + out zeroing in one launch
  prep_kernel<<<dim3(16, 16, 26), dim3(256), 0, stream>>>(
      w1, w3, w2, x, gw, w13t, w2t, idx2, scale2, out);
  scan_kernel<<<dim3(1), dim3(256), 0, stream>>>(idx2, scale2, ptok, pscale, meta);
  gemm1_kernel<<<dim3(H_DIM / 32, MAX_MT), dim3(256), 0, stream>>>(
      x, w13t, ptok, pscale, meta, h);
  gemm2_kernel<<<dim3(D_DIM / 64, MAX_MT), dim3(256), 0, stream>>>(
      h, w2t, ptok, meta, out);
}